// Round 3
// baseline (692.226 us; speedup 1.0000x reference)
//
#include <hip/hip_runtime.h>
#include <hip/hip_bf16.h>
#include <stdint.h>

#define B_ 16
#define T_ 30
#define H_ 64
#define W_ 44
#define HW_ (H_*W_)            // 2816
#define THW_ (T_*HW_)          // 84480

// padded transposed layout: xt[b][half][t:30][hp:66][wp:46][32 ic] bf16
#define HP_ 66
#define WP_ 46
#define PPLANE_ (HP_*WP_)      // 3036
#define PPOS_ (T_*PPLANE_)     // 91080 pos per (b,half)

// conv tiling: block = 256 thr (4 waves), out tile 4t x 8h x 16w, 64 oc
#define TZ 4
#define TY 8
#define TX 16
#define SZ 6
#define SY 10
#define SX 18
#define NS (SZ*SY*SX)          // 1080 staged spatial rows (64 B each per K-half)

// LDS 16B-chunk swizzle: granule=(4*(s&1) + (kg^SWZ(s)))%8 covers all 8 -> 2-way max
#define SWZ(v) (((v) >> 1) & 3)

typedef __bf16 bf16x8 __attribute__((ext_vector_type(8)));
typedef float f32x4 __attribute__((ext_vector_type(4)));

static __device__ __forceinline__ short f2bf(float f) {
    __hip_bfloat16 h = __float2bfloat16(f);
    union { __hip_bfloat16 b; short s; } u; u.b = h; return u.s;
}

static __device__ __forceinline__ void gload_lds16(const short* g, short* l) {
    __builtin_amdgcn_global_load_lds((const __attribute__((address_space(1))) void*)g,
                                     (__attribute__((address_space(3))) void*)l, 16, 0, 0);
}

// ---------------- kernel 0: transpose x -> padded bf16 layout, fused GAP ----------------
__global__ __launch_bounds__(256) void transpose_kernel(const float* __restrict__ x,
                                                        short* __restrict__ xt,
                                                        float* __restrict__ gap) {
    __shared__ short lb[64*53];            // [ic][w], rows padded to 53 shorts
    __shared__ float gsum[64];
    int blk = blockIdx.x;
    int b = blk / (T_*HP_);
    int r = blk - b*(T_*HP_);
    int t = r / HP_;
    int hp = r - t*HP_;
    int tid = threadIdx.x;
    if (tid < 64) gsum[tid] = 0.f;
    __syncthreads();
    bool interior = (hp >= 1) && (hp <= H_);
    if (interior) {
        int h = hp - 1;
        for (int e = tid; e < 704; e += 256) {        // 64 ic x 11 float4
            int ic = e / 11, q = e - ic*11;
            const float4* p = (const float4*)(x + ((size_t)(b*64 + ic)*T_ + t)*HW_ + h*W_) + q;
            float4 v = *p;
            short4 s4;
            s4.x = f2bf(v.x); s4.y = f2bf(v.y); s4.z = f2bf(v.z); s4.w = f2bf(v.w);
            *(short4*)&lb[ic*53 + q*4] = s4;
            atomicAdd(&gsum[ic], (v.x + v.y) + (v.z + v.w));
        }
    }
    __syncthreads();
    if (interior && tid < 64)
        atomicAdd(&gap[b*64 + tid], gsum[tid] * (1.0f / THW_));
    for (int e = tid; e < WP_*16; e += 256) {         // 46 wp x 16 (4 ic each)
        int wp = e >> 4, i4 = (e & 15) * 4;
        short4 s4 = make_short4(0,0,0,0);
        if (interior && wp >= 1 && wp <= W_) {
            int w = wp - 1;
            s4.x = lb[(i4+0)*53 + w];
            s4.y = lb[(i4+1)*53 + w];
            s4.z = lb[(i4+2)*53 + w];
            s4.w = lb[(i4+3)*53 + w];
        }
        size_t pos = (size_t)t*PPLANE_ + hp*WP_ + wp;
        short* dst = xt + ((size_t)(b*2 + (i4 >> 5))*PPOS_ + pos)*32 + (i4 & 31);
        *(short4*)dst = s4;
    }
}

// ---------------- kernel 2: reduce FC + fc1 + sigmoid ----------------
__global__ __launch_bounds__(256) void fc_kernel(const float* __restrict__ gap,
        const float* __restrict__ w_reduce, const float* __restrict__ b_reduce,
        const float* __restrict__ w_fc1, const float* __restrict__ b_fc1,
        float* __restrict__ h_out) {
    __shared__ float gl[256];
    int t = threadIdx.x;
    {
        int b = t >> 4, j = t & 15;
        float a = b_reduce[j];
        #pragma unroll
        for (int c = 0; c < 64; ++c) a += gap[b*64 + c] * w_reduce[j*64 + c];
        gl[b*16 + j] = a;
    }
    __syncthreads();
    for (int idx = t; idx < 2048; idx += 256) {
        int b = idx >> 7, j = idx & 127;
        float v = b_fc1[j];
        #pragma unroll
        for (int i = 0; i < 16; ++i) v += gl[b*16 + i] * w_fc1[j*16 + i];
        h_out[idx] = 1.0f / (1.0f + expf(-v));
    }
}

// ---------------- kernel 3: dynamic weights bf16 (+ zero block) ----------------
__global__ __launch_bounds__(256) void wdyn_kernel(const float* __restrict__ w_fc2,
        const float* __restrict__ h, short* __restrict__ wdyn, short* __restrict__ zblk) {
    if (blockIdx.x == 0 && threadIdx.x < 128) zblk[threadIdx.x] = 0;
    int b = blockIdx.x / 27, tap = blockIdx.x % 27;
    short* dst = wdyn + ((size_t)b*27 + tap) * 4096;
    for (int e = threadIdx.x; e < 4096; e += 256) {
        int oc = e >> 6, ic = e & 63;
        float wv = w_fc2[(oc*64 + ic)*27 + tap];
        float hv = h[b*128 + 2*oc + (ic >> 5)];
        dst[e] = f2bf(wv * hv);
    }
}

// ---------------- kernel 4: implicit-GEMM dynamic conv3d ----------------
__global__ __launch_bounds__(256, 2) void conv_kernel(const short* __restrict__ xt,
        const short* __restrict__ wdyn, const short* __restrict__ zblk,
        float* __restrict__ out) {
    __shared__ short xs[NS*32 + 256];      // 69,632 B
    __shared__ short wb[2][2048];          // 2 x 4 KB

    int bid = blockIdx.x;
    int b = bid / 192; int r = bid - b*192;
    int tzt = r / 24; r -= tzt*24;
    int tyt = r / 3;  int txt = r - tyt*3;
    int t0 = tzt*TZ, h0 = tyt*TY, w0 = txt*TX;

    int tid = threadIdx.x, wid = tid >> 6, lane = tid & 63;
    int ln = lane & 15, kg = lane >> 4;
    int l4 = lane >> 2, c = lane & 3;

    const short* wdb = wdyn + (size_t)b * 27 * 4096;

    f32x4 acc[4][8];
    #pragma unroll
    for (int mt = 0; mt < 4; ++mt)
        #pragma unroll
        for (int j = 0; j < 8; ++j) acc[mt][j] = f32x4{0.f, 0.f, 0.f, 0.f};

    auto stage_w = [&](int step) {         // each wave stages 1 KB (16 oc rows)
        int tap = step % 27, half = step / 27;
        const short* base = wdb + tap*4096 + half*32;
        short* dst = wb[step & 1];
        int oc = wid*16 + l4;
        gload_lds16(base + oc*64 + ((c ^ SWZ(oc)) * 8), dst + wid*512);
    };
    auto stage_x = [&](int half) {         // 68 insts split across 4 waves
        const short* xbh = xt + (size_t)(b*2 + half) * PPOS_ * 32;
        #pragma unroll 2
        for (int ii = 0; ii < 17; ++ii) {
            int inst = wid*17 + ii;
            int s = inst*16 + l4;
            int z = s / 180; int rr = s - z*180;
            int y = rr / 18; int xx = rr - y*18;
            int t = t0 + z - 1;
            int seg = (c ^ SWZ(s)) * 8;
            const short* src = ((unsigned)t < (unsigned)T_)
                ? xbh + ((size_t)t*PPLANE_ + (h0+y)*WP_ + (w0+xx))*32 + seg
                : zblk + seg;
            gload_lds16(src, xs + inst*512);
        }
    };

    stage_x(0);
    stage_w(0);
    __syncthreads();

    for (int step = 0; step < 54; ++step) {
        int nstep = step + 1;
        if (nstep < 54) stage_w(nstep);

        int tap = step % 27;
        int kd = tap / 9; int rr = tap - kd*9; int kh = rr / 3; int kw = rr - kh*3;
        const short* wbp = wb[step & 1];
        bf16x8 a[4];
        #pragma unroll
        for (int mt = 0; mt < 4; ++mt) {
            int oc = mt*16 + ln;
            a[mt] = *(const bf16x8*)&wbp[oc*32 + ((kg ^ SWZ(oc)) * 8)];
        }
        int sb = (wid + kd)*180 + kh*18 + kw + ln;
        #pragma unroll
        for (int j = 0; j < 8; ++j) {
            int s = sb + j*18;
            bf16x8 bv = *(const bf16x8*)&xs[s*32 + ((kg ^ SWZ(s)) * 8)];
            acc[0][j] = __builtin_amdgcn_mfma_f32_16x16x32_bf16(a[0], bv, acc[0][j], 0, 0, 0);
            acc[1][j] = __builtin_amdgcn_mfma_f32_16x16x32_bf16(a[1], bv, acc[1][j], 0, 0, 0);
            acc[2][j] = __builtin_amdgcn_mfma_f32_16x16x32_bf16(a[2], bv, acc[2][j], 0, 0, 0);
            acc[3][j] = __builtin_amdgcn_mfma_f32_16x16x32_bf16(a[3], bv, acc[3][j], 0, 0, 0);
        }
        __syncthreads();
        if (step == 26) { stage_x(1); __syncthreads(); }
    }

    int t = t0 + wid;
    int wv = w0 + ln;
    if (t < T_ && wv < W_) {
        #pragma unroll
        for (int mt = 0; mt < 4; ++mt) {
            size_t obase = ((size_t)(b*64 + mt*16 + kg*4) * T_ + t) * HW_;
            #pragma unroll
            for (int j = 0; j < 8; ++j) {
                float* o = out + obase + (h0 + j)*W_ + wv;
                #pragma unroll
                for (int ri = 0; ri < 4; ++ri)
                    o[(size_t)ri * THW_] = acc[mt][j][ri];
            }
        }
    }
}

extern "C" void kernel_launch(void* const* d_in, const int* in_sizes, int n_in,
                              void* d_out, int out_size, void* d_ws, size_t ws_size,
                              hipStream_t stream) {
    const float* x        = (const float*)d_in[0];
    const float* w_reduce = (const float*)d_in[1];
    const float* b_reduce = (const float*)d_in[2];
    const float* w_fc1    = (const float*)d_in[3];
    const float* b_fc1    = (const float*)d_in[4];
    const float* w_fc2    = (const float*)d_in[5];
    float* out = (float*)d_out;

    // ws layout: gap 4KB | h 8KB | wdyn 3.375MB | zblk 256B | xt 186.5MB (+slack)
    float* gap  = (float*)d_ws;
    float* h    = gap + 1024;
    short* wdyn = (short*)(h + 2048);
    short* zblk = wdyn + (size_t)B_*27*4096;
    short* xt   = zblk + 128;

    hipMemsetAsync(gap, 0, 1024*sizeof(float), stream);   // atomic accumulator
    transpose_kernel<<<B_*T_*HP_, 256, 0, stream>>>(x, xt, gap);
    fc_kernel       <<<1,         256, 0, stream>>>(gap, w_reduce, b_reduce, w_fc1, b_fc1, h);
    wdyn_kernel     <<<B_*27,     256, 0, stream>>>(w_fc2, h, wdyn, zblk);
    conv_kernel     <<<B_*192,    256, 0, stream>>>(xt, wdyn, zblk, out);
}